// Round 1
// baseline (5067.243 us; speedup 1.0000x reference)
//
#include <hip/hip_runtime.h>
#include <cstdint>
#include <cstddef>
#include <math.h>

#define NN 50000
#define NE 800000
#define INC 512
#define HIDC 256
#define GT 401  // 10 + 25 + 16 + 350

// ---------------- degree / norm ----------------
__global__ void k_init_deg(float* deg, int n) {
    int i = blockIdx.x * 256 + threadIdx.x;
    if (i < n) deg[i] = 1.0f;  // self-loop
}
__global__ void k_deg_count(const int* __restrict__ dst, float* deg, int e) {
    int i = blockIdx.x * 256 + threadIdx.x;
    if (i < e) atomicAdd(&deg[dst[i]], 1.0f);
}
__global__ void k_dinv(float* deg, int n) {
    int i = blockIdx.x * 256 + threadIdx.x;
    if (i < n) deg[i] = rsqrtf(deg[i]);
}

// ---------------- tiled fp32 GEMM: C[M x storeN] = A[M x K] * B[K x ldb] ----------------
__global__ __launch_bounds__(256) void gemm64(
    const float* __restrict__ A, const float* __restrict__ B, float* __restrict__ C,
    int M, int K, int ldb, int ldc, int storeN)
{
    __shared__ float As[16][68];  // [k][row], pad 68 -> 16B-aligned rows, spread banks
    __shared__ float Bs[16][64];  // [k][col]
    const int t  = threadIdx.x;
    const int tx = t & 15, ty = t >> 4;
    const int row0 = blockIdx.y * 64, col0 = blockIdx.x * 64;
    const int lr  = t >> 2;          // A tile row 0..63
    const int lk  = (t & 3) * 4;     // A k offset
    const int bkr = t >> 4;          // B tile k row 0..15
    const int bc4 = (t & 15) * 4;    // B col offset

    float acc[4][4] = {};
    for (int k0 = 0; k0 < K; k0 += 16) {
        float4 av = make_float4(0.f, 0.f, 0.f, 0.f);
        if (row0 + lr < M)
            av = *(const float4*)(A + (size_t)(row0 + lr) * K + k0 + lk);
        As[lk + 0][lr] = av.x; As[lk + 1][lr] = av.y;
        As[lk + 2][lr] = av.z; As[lk + 3][lr] = av.w;
        float4 bv = *(const float4*)(B + (size_t)(k0 + bkr) * ldb + col0 + bc4);
        *(float4*)&Bs[bkr][bc4] = bv;
        __syncthreads();
#pragma unroll
        for (int kk = 0; kk < 16; ++kk) {
            float a[4], b[4];
#pragma unroll
            for (int i = 0; i < 4; ++i) a[i] = As[kk][ty * 4 + i];
#pragma unroll
            for (int j = 0; j < 4; ++j) b[j] = Bs[kk][tx * 4 + j];
#pragma unroll
            for (int i = 0; i < 4; ++i)
#pragma unroll
                for (int j = 0; j < 4; ++j) acc[i][j] += a[i] * b[j];
        }
        __syncthreads();
    }
#pragma unroll
    for (int i = 0; i < 4; ++i) {
        int r = row0 + ty * 4 + i;
        if (r >= M) continue;
#pragma unroll
        for (int j = 0; j < 4; ++j) {
            int c = col0 + tx * 4 + j;
            if (c < storeN) C[(size_t)r * ldc + c] = acc[i][j];
        }
    }
}

// ---------------- layer 1 ----------------
__global__ void k_init_h(const float* __restrict__ xw, const float* __restrict__ dinv,
                         const float* __restrict__ b1, float* __restrict__ h)
{
    int i = blockIdx.x, c = threadIdx.x;
    float d = dinv[i];
    h[(size_t)i * HIDC + c] = xw[(size_t)i * HIDC + c] * d * d + b1[c];
}

__global__ void k_scatter1(const float* __restrict__ xw, const int* __restrict__ src,
                           const int* __restrict__ dst, const float* __restrict__ dinv,
                           float* __restrict__ h)
{
    int e = (blockIdx.x * blockDim.x + threadIdx.x) >> 6;
    if (e >= NE) return;
    int lane = threadIdx.x & 63;
    int s = src[e], d = dst[e];
    float norm = dinv[s] * dinv[d];
    float4 v = *(const float4*)(xw + (size_t)s * HIDC + lane * 4);
    float* hd = h + (size_t)d * HIDC + lane * 4;
    atomicAdd(hd + 0, v.x * norm);
    atomicAdd(hd + 1, v.y * norm);
    atomicAdd(hd + 2, v.z * norm);
    atomicAdd(hd + 3, v.w * norm);
}

__global__ void k_relu(float* __restrict__ h)
{
    size_t idx = (size_t)blockIdx.x * 256 + threadIdx.x;
    h[idx] = fmaxf(h[idx], 0.f);
}

// ---------------- pack head weights: Wall[256][448] (zero padded), ball[448] ----------------
__global__ void k_pack(const float* __restrict__ Wg0, const float* __restrict__ Wg1,
                       const float* __restrict__ Wg2, const float* __restrict__ Wg3,
                       const float* __restrict__ bg0, const float* __restrict__ bg1,
                       const float* __restrict__ bg2, const float* __restrict__ bg3,
                       float* __restrict__ Wall, float* __restrict__ ball)
{
    int t = blockIdx.x * 256 + threadIdx.x;
    if (t < 256 * 448) {
        int k = t / 448, j = t % 448;
        float v = 0.f;
        if (j < 10)       v = Wg0[k * 10 + j];
        else if (j < 35)  v = Wg1[k * 25 + (j - 10)];
        else if (j < 51)  v = Wg2[k * 16 + (j - 35)];
        else if (j < 401) v = Wg3[k * 350 + (j - 51)];
        Wall[t] = v;
    }
    if (t < 448) {
        float v = 0.f;
        if (t < 10)       v = bg0[t];
        else if (t < 35)  v = bg1[t - 10];
        else if (t < 51)  v = bg2[t - 35];
        else if (t < 401) v = bg3[t - 51];
        ball[t] = v;
    }
}

// ---------------- head aggregation ----------------
__global__ void k_init_gagg(const float* __restrict__ g, const float* __restrict__ dinv,
                            const float* __restrict__ ball,
                            float* __restrict__ o0, float* __restrict__ o1,
                            float* __restrict__ o2, float* __restrict__ o3)
{
    int t = blockIdx.x * 256 + threadIdx.x;
    if (t >= NN * GT) return;
    int i = t / GT, j = t % GT;
    float d = dinv[i];
    float v = g[(size_t)i * GT + j] * d * d + ball[j];
    if (j < 10)       o0[i * 10 + j] = v;
    else if (j < 35)  o1[i * 25 + (j - 10)] = v;
    else if (j < 51)  o2[i * 16 + (j - 35)] = v;
    else              o3[(size_t)i * 350 + (j - 51)] = v;
}

__global__ void k_scatter2(const float* __restrict__ g, const int* __restrict__ src,
                           const int* __restrict__ dst, const float* __restrict__ dinv,
                           float* __restrict__ o0, float* __restrict__ o1,
                           float* __restrict__ o2, float* __restrict__ o3)
{
    int e = (blockIdx.x * blockDim.x + threadIdx.x) >> 6;
    if (e >= NE) return;
    int lane = threadIdx.x & 63;
    int s = src[e], d = dst[e];
    float norm = dinv[s] * dinv[d];
    const float* grow = g + (size_t)s * GT;
    for (int j = lane; j < GT; j += 64) {
        float v = grow[j] * norm;
        if (j < 10)       atomicAdd(&o0[d * 10 + j], v);
        else if (j < 35)  atomicAdd(&o1[d * 25 + (j - 10)], v);
        else if (j < 51)  atomicAdd(&o2[d * 16 + (j - 35)], v);
        else              atomicAdd(&o3[(size_t)d * 350 + (j - 51)], v);
    }
}

// ---------------- final heads: softmax(g @ Wc + bc), in-place on d_out ----------------
template <int NC>
__global__ void k_head_small(const float* __restrict__ Wc, const float* __restrict__ bc,
                             float* __restrict__ io, int n)
{
    int wid  = (blockIdx.x * blockDim.x + threadIdx.x) >> 6;
    int lane = threadIdx.x & 63;
    if (wid >= n) return;
    const float* row = io + (size_t)wid * NC;
    float rv = (lane < NC) ? row[lane] : 0.f;
    float logit = (lane < NC) ? bc[lane] : -INFINITY;
#pragma unroll
    for (int k = 0; k < NC; ++k) {
        float a = __shfl(rv, k);
        if (lane < NC) logit += a * Wc[k * NC + lane];
    }
    float m = logit;
    for (int off = 32; off; off >>= 1) m = fmaxf(m, __shfl_xor(m, off));
    float e = (lane < NC) ? __expf(logit - m) : 0.f;
    float s = e;
    for (int off = 32; off; off >>= 1) s += __shfl_xor(s, off);
    if (lane < NC) io[(size_t)wid * NC + lane] = e / s;
}

#define NB 8
__global__ __launch_bounds__(256) void k_head_author(
    const float* __restrict__ Wc, const float* __restrict__ bc,
    float* __restrict__ io, int n)
{
    __shared__ float rows[NB][350];
    __shared__ float logits[NB][350];
    __shared__ float red[4];
    int node0 = blockIdx.x * NB;
    int tid = threadIdx.x;
    int lane = tid & 63, wid = tid >> 6;

    for (int idx = tid; idx < NB * 350; idx += 256) {
        int r = idx / 350, c = idx % 350;
        rows[r][c] = io[(size_t)(node0 + r) * 350 + c];
    }
    __syncthreads();

    for (int j = tid; j < 350; j += 256) {
        float acc[NB];
        float b = bc[j];
#pragma unroll
        for (int r = 0; r < NB; ++r) acc[r] = b;
        for (int k = 0; k < 350; ++k) {
            float w = Wc[k * 350 + j];
#pragma unroll
            for (int r = 0; r < NB; ++r) acc[r] += rows[r][k] * w;
        }
#pragma unroll
        for (int r = 0; r < NB; ++r) logits[r][j] = acc[r];
    }
    __syncthreads();

    for (int r = 0; r < NB; ++r) {
        float m = -INFINITY;
        for (int j = tid; j < 350; j += 256) m = fmaxf(m, logits[r][j]);
        for (int off = 32; off; off >>= 1) m = fmaxf(m, __shfl_xor(m, off));
        if (lane == 0) red[wid] = m;
        __syncthreads();
        m = fmaxf(fmaxf(red[0], red[1]), fmaxf(red[2], red[3]));
        __syncthreads();
        float s = 0.f;
        for (int j = tid; j < 350; j += 256) s += __expf(logits[r][j] - m);
        for (int off = 32; off; off >>= 1) s += __shfl_xor(s, off);
        if (lane == 0) red[wid] = s;
        __syncthreads();
        s = red[0] + red[1] + red[2] + red[3];
        for (int j = tid; j < 350; j += 256)
            io[(size_t)(node0 + r) * 350 + j] = __expf(logits[r][j] - m) / s;
        __syncthreads();
    }
}

// ---------------- launch ----------------
extern "C" void kernel_launch(void* const* d_in, const int* in_sizes, int n_in,
                              void* d_out, int out_size, void* d_ws, size_t ws_size,
                              hipStream_t stream)
{
    const float* x   = (const float*)d_in[0];
    const int*   ei  = (const int*)d_in[1];
    const float* W1  = (const float*)d_in[2];
    const float* b1  = (const float*)d_in[3];
    const float* Wg0 = (const float*)d_in[4];
    const float* bg0 = (const float*)d_in[5];
    const float* Wc0 = (const float*)d_in[6];
    const float* bc0 = (const float*)d_in[7];
    const float* Wg1 = (const float*)d_in[8];
    const float* bg1 = (const float*)d_in[9];
    const float* Wc1 = (const float*)d_in[10];
    const float* bc1 = (const float*)d_in[11];
    const float* Wg2 = (const float*)d_in[12];
    const float* bg2 = (const float*)d_in[13];
    const float* Wc2 = (const float*)d_in[14];
    const float* bc2 = (const float*)d_in[15];
    const float* Wg3 = (const float*)d_in[16];
    const float* bg3 = (const float*)d_in[17];
    const float* Wc3 = (const float*)d_in[18];
    const float* bc3 = (const float*)d_in[19];
    const int* srcI = ei;
    const int* dstI = ei + NE;

    float* ws = (float*)d_ws;
    size_t off = 0;
    float* dinv = ws + off; off += 50176;                 // deg -> dinv
    float* xw   = ws + off; off += (size_t)NN * HIDC;     // x @ W1
    float* hb   = ws + off; off += (size_t)NN * HIDC;     // relu(gcn1)
    float* gb   = ws + off; off += (size_t)NN * GT;       // h @ Wg_all
    float* Wall = ws + off; off += 256 * 448;
    float* ball = ws + off; off += 448;

    float* out0 = (float*)d_out;
    float* out1 = out0 + (size_t)NN * 10;
    float* out2 = out1 + (size_t)NN * 25;
    float* out3 = out2 + (size_t)NN * 16;

    // degree / dinv
    k_init_deg<<<(NN + 255) / 256, 256, 0, stream>>>(dinv, NN);
    k_deg_count<<<(NE + 255) / 256, 256, 0, stream>>>(dstI, dinv, NE);
    k_dinv<<<(NN + 255) / 256, 256, 0, stream>>>(dinv, NN);

    // layer 1: xw = x @ W1 ; h = relu(scatter + selfloop + b1)
    gemm64<<<dim3(HIDC / 64, (NN + 63) / 64), 256, 0, stream>>>(x, W1, xw, NN, INC, HIDC, HIDC, HIDC);
    k_init_h<<<NN, 256, 0, stream>>>(xw, dinv, b1, hb);
    k_scatter1<<<NE / 4, 256, 0, stream>>>(xw, srcI, dstI, dinv, hb);
    k_relu<<<NN, 256, 0, stream>>>(hb);

    // heads: g_all = h @ Wg_all  (packed, zero-padded to 448 cols)
    k_pack<<<448, 256, 0, stream>>>(Wg0, Wg1, Wg2, Wg3, bg0, bg1, bg2, bg3, Wall, ball);
    gemm64<<<dim3(448 / 64, (NN + 63) / 64), 256, 0, stream>>>(hb, Wall, gb, NN, HIDC, 448, GT, GT);
    k_init_gagg<<<(NN * GT + 255) / 256, 256, 0, stream>>>(gb, dinv, ball, out0, out1, out2, out3);
    k_scatter2<<<NE / 4, 256, 0, stream>>>(gb, srcI, dstI, dinv, out0, out1, out2, out3);

    // per-head classifier + softmax (in place on d_out)
    k_head_small<10><<<NN / 4, 256, 0, stream>>>(Wc0, bc0, out0, NN);
    k_head_small<25><<<NN / 4, 256, 0, stream>>>(Wc1, bc1, out1, NN);
    k_head_small<16><<<NN / 4, 256, 0, stream>>>(Wc2, bc2, out2, NN);
    k_head_author<<<NN / NB, 256, 0, stream>>>(Wc3, bc3, out3, NN);
}

// Round 2
// 1291.809 us; speedup vs baseline: 3.9226x; 3.9226x over previous
//
#include <hip/hip_runtime.h>
#include <cstdint>
#include <cstddef>
#include <math.h>

#define NN 50000
#define NE 800000
#define INC 512
#define HIDC 256
#define GT 448   // padded head width: 10+25+16+350=401 -> 448
#define NBLK ((NN + 255) / 256)   // 196 scan blocks

// ---------------- zero ints ----------------
__global__ void k_zero_i(int* a, int n) {
    int i = blockIdx.x * 256 + threadIdx.x;
    if (i < n) a[i] = 0;
}

// ---------------- degree count (int atomics) ----------------
__global__ void k_deg_count(const int* __restrict__ dst, int* __restrict__ cnt, int e) {
    int i = blockIdx.x * 256 + threadIdx.x;
    if (i < e) atomicAdd(&cnt[dst[i]], 1);
}

__global__ void k_dinv(const int* __restrict__ cnt, float* __restrict__ dinv, int n) {
    int i = blockIdx.x * 256 + threadIdx.x;
    if (i < n) dinv[i] = rsqrtf((float)cnt[i] + 1.0f);
}

// ---------------- exclusive scan (3-phase) ----------------
__global__ void k_scan1(const int* __restrict__ cnt, int* __restrict__ excl,
                        int* __restrict__ bsum, int n) {
    __shared__ int s[256];
    int i = blockIdx.x * 256 + threadIdx.x;
    int v = (i < n) ? cnt[i] : 0;
    s[threadIdx.x] = v;
    __syncthreads();
    for (int off = 1; off < 256; off <<= 1) {
        int t = (threadIdx.x >= off) ? s[threadIdx.x - off] : 0;
        __syncthreads();
        s[threadIdx.x] += t;
        __syncthreads();
    }
    if (i < n) excl[i] = s[threadIdx.x] - v;
    if (threadIdx.x == 255) bsum[blockIdx.x] = s[255];
}

__global__ void k_scan2(int* __restrict__ bsum, int* __restrict__ bsumx, int nb) {
    __shared__ int s[256];
    int t = threadIdx.x;
    int v = (t < nb) ? bsum[t] : 0;
    s[t] = v;
    __syncthreads();
    for (int off = 1; off < 256; off <<= 1) {
        int tt = (t >= off) ? s[t - off] : 0;
        __syncthreads();
        s[t] += tt;
        __syncthreads();
    }
    if (t < nb) bsumx[t] = s[t] - v;
}

__global__ void k_scan3(int* __restrict__ rowptr, const int* __restrict__ bsumx, int n, int e) {
    int i = blockIdx.x * 256 + threadIdx.x;
    if (i < n) rowptr[i] += bsumx[blockIdx.x];
    if (i == 0) rowptr[n] = e;
}

// ---------------- CSR fill ----------------
__global__ void k_fill(const int* __restrict__ src, const int* __restrict__ dst,
                       const int* __restrict__ rowptr, int* __restrict__ cursor,
                       int* __restrict__ col, int e) {
    int i = blockIdx.x * 256 + threadIdx.x;
    if (i >= e) return;
    int d = dst[i];
    int pos = rowptr[d] + atomicAdd(&cursor[d], 1);
    col[pos] = src[i];
}

// ---------------- gather aggregation: out = dinv_i * sum dinv_j*feat_j + dinv_i^2*feat_i (+b)(relu) ----------------
template <bool RELU, bool BIAS>
__global__ __launch_bounds__(256) void k_gather(
    const float* __restrict__ feat, const int* __restrict__ rowptr,
    const int* __restrict__ col, const float* __restrict__ dinv,
    const float* __restrict__ bias, float* __restrict__ out, int n)
{
    int wid  = (blockIdx.x * 256 + threadIdx.x) >> 6;
    int lane = threadIdx.x & 63;
    if (wid >= n) return;
    float di = dinv[wid];
    int p0 = rowptr[wid], p1 = rowptr[wid + 1];
    float4 acc = make_float4(0.f, 0.f, 0.f, 0.f);
#pragma unroll 2
    for (int p = p0; p < p1; ++p) {
        int j = __builtin_amdgcn_readfirstlane(col[p]);
        float dj = dinv[j];
        float4 v = *(const float4*)(feat + (size_t)j * HIDC + lane * 4);
        acc.x += dj * v.x; acc.y += dj * v.y;
        acc.z += dj * v.z; acc.w += dj * v.w;
    }
    float4 sv = *(const float4*)(feat + (size_t)wid * HIDC + lane * 4);
    float4 r;
    r.x = di * acc.x + di * di * sv.x;
    r.y = di * acc.y + di * di * sv.y;
    r.z = di * acc.z + di * di * sv.z;
    r.w = di * acc.w + di * di * sv.w;
    if (BIAS) {
        const float4 b = *(const float4*)(bias + lane * 4);
        r.x += b.x; r.y += b.y; r.z += b.z; r.w += b.w;
    }
    if (RELU) {
        r.x = fmaxf(r.x, 0.f); r.y = fmaxf(r.y, 0.f);
        r.z = fmaxf(r.z, 0.f); r.w = fmaxf(r.w, 0.f);
    }
    *(float4*)(out + (size_t)wid * HIDC + lane * 4) = r;
}

// ---------------- tiled fp32 GEMM: C[M x N] = A[M x K] * B[K x ldb] (+bias) ----------------
__global__ __launch_bounds__(256) void gemm64(
    const float* __restrict__ A, const float* __restrict__ B, float* __restrict__ C,
    const float* __restrict__ bias, int M, int K, int ldb, int ldc)
{
    __shared__ float As[16][68];
    __shared__ float Bs[16][64];
    const int t  = threadIdx.x;
    const int tx = t & 15, ty = t >> 4;
    const int row0 = blockIdx.y * 64, col0 = blockIdx.x * 64;
    const int lr  = t >> 2;
    const int lk  = (t & 3) * 4;
    const int bkr = t >> 4;
    const int bc4 = (t & 15) * 4;

    float acc[4][4] = {};
    for (int k0 = 0; k0 < K; k0 += 16) {
        float4 av = make_float4(0.f, 0.f, 0.f, 0.f);
        if (row0 + lr < M)
            av = *(const float4*)(A + (size_t)(row0 + lr) * K + k0 + lk);
        As[lk + 0][lr] = av.x; As[lk + 1][lr] = av.y;
        As[lk + 2][lr] = av.z; As[lk + 3][lr] = av.w;
        float4 bv = *(const float4*)(B + (size_t)(k0 + bkr) * ldb + col0 + bc4);
        *(float4*)&Bs[bkr][bc4] = bv;
        __syncthreads();
#pragma unroll
        for (int kk = 0; kk < 16; ++kk) {
            float a[4], b[4];
#pragma unroll
            for (int i = 0; i < 4; ++i) a[i] = As[kk][ty * 4 + i];
#pragma unroll
            for (int j = 0; j < 4; ++j) b[j] = Bs[kk][tx * 4 + j];
#pragma unroll
            for (int i = 0; i < 4; ++i)
#pragma unroll
                for (int j = 0; j < 4; ++j) acc[i][j] += a[i] * b[j];
        }
        __syncthreads();
    }
#pragma unroll
    for (int i = 0; i < 4; ++i) {
        int r = row0 + ty * 4 + i;
        if (r >= M) continue;
#pragma unroll
        for (int j = 0; j < 4; ++j) {
            int c = col0 + tx * 4 + j;
            float bv = bias ? bias[c] : 0.f;
            C[(size_t)r * ldc + c] = acc[i][j] + bv;
        }
    }
}

// ---------------- pack head weights: Wall[256][448] (zero padded), ball[448] ----------------
__global__ void k_pack(const float* __restrict__ Wg0, const float* __restrict__ Wg1,
                       const float* __restrict__ Wg2, const float* __restrict__ Wg3,
                       const float* __restrict__ bg0, const float* __restrict__ bg1,
                       const float* __restrict__ bg2, const float* __restrict__ bg3,
                       float* __restrict__ Wall, float* __restrict__ ball)
{
    int t = blockIdx.x * 256 + threadIdx.x;
    if (t < 256 * 448) {
        int k = t / 448, j = t % 448;
        float v = 0.f;
        if (j < 10)       v = Wg0[k * 10 + j];
        else if (j < 35)  v = Wg1[k * 25 + (j - 10)];
        else if (j < 51)  v = Wg2[k * 16 + (j - 35)];
        else if (j < 401) v = Wg3[k * 350 + (j - 51)];
        Wall[t] = v;
    }
    if (t < 448) {
        float v = 0.f;
        if (t < 10)       v = bg0[t];
        else if (t < 35)  v = bg1[t - 10];
        else if (t < 51)  v = bg2[t - 35];
        else if (t < 401) v = bg3[t - 51];
        ball[t] = v;
    }
}

// ---------------- final heads: softmax(g @ Wc + bc) ----------------
template <int NC, int OFF>
__global__ void k_head_small(const float* __restrict__ gb, const float* __restrict__ Wc,
                             const float* __restrict__ bc, float* __restrict__ out, int n)
{
    int wid  = (blockIdx.x * blockDim.x + threadIdx.x) >> 6;
    int lane = threadIdx.x & 63;
    if (wid >= n) return;
    const float* row = gb + (size_t)wid * GT + OFF;
    float rv = (lane < NC) ? row[lane] : 0.f;
    float logit = (lane < NC) ? bc[lane] : -INFINITY;
#pragma unroll
    for (int k = 0; k < NC; ++k) {
        float a = __shfl(rv, k);
        if (lane < NC) logit += a * Wc[k * NC + lane];
    }
    float m = logit;
    for (int off = 32; off; off >>= 1) m = fmaxf(m, __shfl_xor(m, off));
    float e = (lane < NC) ? __expf(logit - m) : 0.f;
    float s = e;
    for (int off = 32; off; off >>= 1) s += __shfl_xor(s, off);
    if (lane < NC) out[(size_t)wid * NC + lane] = e / s;
}

#define NB 8
__global__ __launch_bounds__(256) void k_head_author(
    const float* __restrict__ gb, const float* __restrict__ Wc,
    const float* __restrict__ bc, float* __restrict__ out, int n)
{
    __shared__ float rows[NB][350];
    __shared__ float logits[NB][350];
    __shared__ float red[4];
    int node0 = blockIdx.x * NB;
    int tid = threadIdx.x;
    int lane = tid & 63, wid = tid >> 6;

    for (int idx = tid; idx < NB * 350; idx += 256) {
        int r = idx / 350, c = idx % 350;
        rows[r][c] = gb[(size_t)(node0 + r) * GT + 51 + c];
    }
    __syncthreads();

    for (int j = tid; j < 350; j += 256) {
        float acc[NB];
        float b = bc[j];
#pragma unroll
        for (int r = 0; r < NB; ++r) acc[r] = b;
        for (int k = 0; k < 350; ++k) {
            float w = Wc[k * 350 + j];
#pragma unroll
            for (int r = 0; r < NB; ++r) acc[r] += rows[r][k] * w;
        }
#pragma unroll
        for (int r = 0; r < NB; ++r) logits[r][j] = acc[r];
    }
    __syncthreads();

    for (int r = 0; r < NB; ++r) {
        float m = -INFINITY;
        for (int j = tid; j < 350; j += 256) m = fmaxf(m, logits[r][j]);
        for (int off = 32; off; off >>= 1) m = fmaxf(m, __shfl_xor(m, off));
        if (lane == 0) red[wid] = m;
        __syncthreads();
        m = fmaxf(fmaxf(red[0], red[1]), fmaxf(red[2], red[3]));
        __syncthreads();
        float s = 0.f;
        for (int j = tid; j < 350; j += 256) s += __expf(logits[r][j] - m);
        for (int off = 32; off; off >>= 1) s += __shfl_xor(s, off);
        if (lane == 0) red[wid] = s;
        __syncthreads();
        s = red[0] + red[1] + red[2] + red[3];
        for (int j = tid; j < 350; j += 256)
            out[(size_t)(node0 + r) * 350 + j] = __expf(logits[r][j] - m) / s;
        __syncthreads();
    }
}

// ---------------- launch ----------------
extern "C" void kernel_launch(void* const* d_in, const int* in_sizes, int n_in,
                              void* d_out, int out_size, void* d_ws, size_t ws_size,
                              hipStream_t stream)
{
    const float* x   = (const float*)d_in[0];
    const int*   ei  = (const int*)d_in[1];
    const float* W1  = (const float*)d_in[2];
    const float* b1  = (const float*)d_in[3];
    const float* Wg0 = (const float*)d_in[4];
    const float* bg0 = (const float*)d_in[5];
    const float* Wc0 = (const float*)d_in[6];
    const float* bc0 = (const float*)d_in[7];
    const float* Wg1 = (const float*)d_in[8];
    const float* bg1 = (const float*)d_in[9];
    const float* Wc1 = (const float*)d_in[10];
    const float* bc1 = (const float*)d_in[11];
    const float* Wg2 = (const float*)d_in[12];
    const float* bg2 = (const float*)d_in[13];
    const float* Wc2 = (const float*)d_in[14];
    const float* bc2 = (const float*)d_in[15];
    const float* Wg3 = (const float*)d_in[16];
    const float* bg3 = (const float*)d_in[17];
    const float* Wc3 = (const float*)d_in[18];
    const float* bc3 = (const float*)d_in[19];
    const int* srcI = ei;
    const int* dstI = ei + NE;

    char* ws = (char*)d_ws;
    size_t off = 0;
    auto alloc = [&](size_t elems) { void* p = ws + off; off += elems * 4; return p; };
    float* dinv   = (float*)alloc(50176);
    int*   rowptr = (int*)  alloc(50432);     // NN+1
    int*   cnt    = (int*)  alloc(50176);
    int*   cursor = (int*)  alloc(50176);
    int*   bsum   = (int*)  alloc(256);
    int*   bsumx  = (int*)  alloc(256);
    int*   col    = (int*)  alloc(NE);
    float* xw     = (float*)alloc((size_t)NN * HIDC);  // reused as ah
    float* hb     = (float*)alloc((size_t)NN * HIDC);
    float* gb     = (float*)alloc((size_t)NN * GT);
    float* Wall   = (float*)alloc(256 * GT);
    float* ball   = (float*)alloc(GT);
    float* ah = xw;  // alias: xw dead after gather1

    float* out0 = (float*)d_out;
    float* out1 = out0 + (size_t)NN * 10;
    float* out2 = out1 + (size_t)NN * 25;
    float* out3 = out2 + (size_t)NN * 16;

    // ---- CSR build ----
    k_zero_i<<<(2 * 50176 + 255) / 256, 256, 0, stream>>>(cnt, 2 * 50176);  // cnt+cursor adjacent
    k_deg_count<<<(NE + 255) / 256, 256, 0, stream>>>(dstI, cnt, NE);
    k_dinv<<<NBLK, 256, 0, stream>>>(cnt, dinv, NN);
    k_scan1<<<NBLK, 256, 0, stream>>>(cnt, rowptr, bsum, NN);
    k_scan2<<<1, 256, 0, stream>>>(bsum, bsumx, NBLK);
    k_scan3<<<NBLK, 256, 0, stream>>>(rowptr, bsumx, NN, NE);
    k_fill<<<(NE + 255) / 256, 256, 0, stream>>>(srcI, dstI, rowptr, cursor, col, NE);

    // ---- layer 1: xw = x@W1 ; h = relu(gather(xw) + b1) ----
    gemm64<<<dim3(HIDC / 64, (NN + 63) / 64), 256, 0, stream>>>(x, W1, xw, nullptr, NN, INC, HIDC, HIDC);
    k_gather<true, true><<<(NN + 3) / 4, 256, 0, stream>>>(xw, rowptr, col, dinv, b1, hb, NN);

    // ---- heads: ah = gather(h) ; g_all = ah @ Wall + ball ----
    k_gather<false, false><<<(NN + 3) / 4, 256, 0, stream>>>(hb, rowptr, col, dinv, nullptr, ah, NN);
    k_pack<<<448, 256, 0, stream>>>(Wg0, Wg1, Wg2, Wg3, bg0, bg1, bg2, bg3, Wall, ball);
    gemm64<<<dim3(GT / 64, (NN + 63) / 64), 256, 0, stream>>>(ah, Wall, gb, ball, NN, HIDC, GT, GT);

    // ---- per-head classifier + softmax ----
    k_head_small<10, 0 ><<<(NN + 3) / 4, 256, 0, stream>>>(gb, Wc0, bc0, out0, NN);
    k_head_small<25, 10><<<(NN + 3) / 4, 256, 0, stream>>>(gb, Wc1, bc1, out1, NN);
    k_head_small<16, 35><<<(NN + 3) / 4, 256, 0, stream>>>(gb, Wc2, bc2, out2, NN);
    k_head_author<<<NN / NB, 256, 0, stream>>>(gb, Wc3, bc3, out3, NN);
}

// Round 3
// 494.168 us; speedup vs baseline: 10.2541x; 2.6141x over previous
//
#include <hip/hip_runtime.h>
#include <hip/hip_bf16.h>
#include <cstdint>
#include <cstddef>
#include <math.h>

#define NN 50000
#define NE 800000
#define INC 512
#define HIDC 256
#define GT 448   // packed head width: author 0..349, pad, type 352.., school 362.., time 387..402
#define NBLK ((NN + 255) / 256)

typedef __attribute__((ext_vector_type(8))) short s8v;   // 8 bf16 = 4 VGPR
typedef __attribute__((ext_vector_type(4))) float f4v;

__device__ __forceinline__ float b2f(unsigned short u) {
    return __uint_as_float(((unsigned)u) << 16);
}
__device__ __forceinline__ unsigned short f2b(float f) {
    __hip_bfloat16 h = __float2bfloat16(f);
    return *reinterpret_cast<unsigned short*>(&h);
}

// ---------------- CSR build ----------------
__global__ void k_zero_i(int* a, int n) {
    int i = blockIdx.x * 256 + threadIdx.x;
    if (i < n) a[i] = 0;
}
__global__ void k_deg_count(const int* __restrict__ dst, int* __restrict__ cnt, int e) {
    int i = blockIdx.x * 256 + threadIdx.x;
    if (i < e) atomicAdd(&cnt[dst[i]], 1);
}
__global__ void k_dinv(const int* __restrict__ cnt, float* __restrict__ dinv, int n) {
    int i = blockIdx.x * 256 + threadIdx.x;
    if (i < n) dinv[i] = rsqrtf((float)cnt[i] + 1.0f);
}
__global__ void k_scan1(const int* __restrict__ cnt, int* __restrict__ excl,
                        int* __restrict__ bsum, int n) {
    __shared__ int s[256];
    int i = blockIdx.x * 256 + threadIdx.x;
    int v = (i < n) ? cnt[i] : 0;
    s[threadIdx.x] = v;
    __syncthreads();
    for (int off = 1; off < 256; off <<= 1) {
        int t = (threadIdx.x >= off) ? s[threadIdx.x - off] : 0;
        __syncthreads();
        s[threadIdx.x] += t;
        __syncthreads();
    }
    if (i < n) excl[i] = s[threadIdx.x] - v;
    if (threadIdx.x == 255) bsum[blockIdx.x] = s[255];
}
__global__ void k_scan2(int* __restrict__ bsum, int* __restrict__ bsumx, int nb) {
    __shared__ int s[256];
    int t = threadIdx.x;
    int v = (t < nb) ? bsum[t] : 0;
    s[t] = v;
    __syncthreads();
    for (int off = 1; off < 256; off <<= 1) {
        int tt = (t >= off) ? s[t - off] : 0;
        __syncthreads();
        s[t] += tt;
        __syncthreads();
    }
    if (t < nb) bsumx[t] = s[t] - v;
}
__global__ void k_scan3(int* __restrict__ rowptr, const int* __restrict__ bsumx, int n, int e) {
    int i = blockIdx.x * 256 + threadIdx.x;
    if (i < n) rowptr[i] += bsumx[blockIdx.x];
    if (i == 0) rowptr[n] = e;
}
__global__ void k_fill(const int* __restrict__ src, const int* __restrict__ dst,
                       const int* __restrict__ rowptr, int* __restrict__ cursor,
                       int* __restrict__ col, int e) {
    int i = blockIdx.x * 256 + threadIdx.x;
    if (i >= e) return;
    int d = dst[i];
    int pos = rowptr[d] + atomicAdd(&cursor[d], 1);
    col[pos] = src[i];
}

// ---------------- fp32 -> bf16 convert (x) ----------------
__global__ void k_f2b(const float* __restrict__ in, unsigned short* __restrict__ out, int n4) {
    int t = blockIdx.x * 256 + threadIdx.x;
    if (t >= n4) return;
    float4 v = ((const float4*)in)[t];
    ushort4 o;
    o.x = f2b(v.x); o.y = f2b(v.y); o.z = f2b(v.z); o.w = f2b(v.w);
    ((ushort4*)out)[t] = o;
}

// ---------------- weight packs ----------------
__global__ void k_packW1t(const float* __restrict__ W1, unsigned short* __restrict__ W1t) {
    int t = blockIdx.x * 256 + threadIdx.x;  // 256*512
    if (t >= 256 * 512) return;
    int c = t >> 9, k = t & 511;
    W1t[t] = f2b(W1[(size_t)k * 256 + c]);
}
__global__ void k_packWall(const float* __restrict__ Wg0, const float* __restrict__ Wg1,
                           const float* __restrict__ Wg2, const float* __restrict__ Wg3,
                           const float* __restrict__ bg0, const float* __restrict__ bg1,
                           const float* __restrict__ bg2, const float* __restrict__ bg3,
                           unsigned short* __restrict__ Wallt, float* __restrict__ ballp) {
    int t = blockIdx.x * 256 + threadIdx.x;  // 448*256
    if (t < 448 * 256) {
        int j = t >> 8, k = t & 255;
        float v = 0.f;
        if (j < 350)      v = Wg3[(size_t)k * 350 + j];
        else if (j < 352) v = 0.f;
        else if (j < 362) v = Wg0[k * 10 + (j - 352)];
        else if (j < 387) v = Wg1[k * 25 + (j - 362)];
        else if (j < 403) v = Wg2[k * 16 + (j - 387)];
        Wallt[t] = f2b(v);
    }
    if (t < 448) {
        float b = 0.f;
        if (t < 350)      b = bg3[t];
        else if (t < 352) b = 0.f;
        else if (t < 362) b = bg0[t - 352];
        else if (t < 387) b = bg1[t - 362];
        else if (t < 403) b = bg2[t - 387];
        ballp[t] = b;
    }
}
__global__ void k_packWc3(const float* __restrict__ Wc3, const float* __restrict__ bc3,
                          unsigned short* __restrict__ Wc3t, float* __restrict__ bc3p) {
    int t = blockIdx.x * 256 + threadIdx.x;  // 384*384
    if (t < 384 * 384) {
        int j = t / 384, k = t - j * 384;
        float v = (j < 350 && k < 350) ? Wc3[(size_t)k * 350 + j] : 0.f;
        Wc3t[t] = f2b(v);
    }
    if (t < 384) bc3p[t] = (t < 350) ? bc3[t] : 0.f;
}

// ---------------- bf16 MFMA GEMM: C[MxN] = A[MxK](bf16) @ Bt[N][K](bf16) + bias ----------------
// BM=128, BN=64 (gridDim.x tiles), BK=64, 256 threads = 4 waves (wave w: rows w*32..w*32+32)
template <bool OUT_BF16>
__global__ __launch_bounds__(256) void mfma_gemm(
    const unsigned short* __restrict__ A, const unsigned short* __restrict__ Bt,
    void* __restrict__ Cout, const float* __restrict__ bias,
    int M, int K, int lda, int ldc)
{
    __shared__ s8v As[1024];  // 128 rows x 8 chunks(16B), chunk XOR-swizzled by row&7
    __shared__ s8v Bs[512];   // 64 cols  x 8 chunks
    const int t = threadIdx.x;
    const int lane = t & 63, wv = t >> 6;
    const int row0 = blockIdx.y * 128;
    const int col0 = blockIdx.x * 64;
    const int l15 = lane & 15, lq = lane >> 4, l7 = lane & 7;

    f4v acc[2][4] = {};
    for (int k0 = 0; k0 < K; k0 += 64) {
#pragma unroll
        for (int s = 0; s < 4; ++s) {   // stage A: 1024 chunks
            int c = s * 256 + t;
            int row = c >> 3, ch = c & 7;
            int chg = ch ^ (row & 7);
            int gr = row0 + row; if (gr >= M) gr = M - 1;
            As[c] = *(const s8v*)(A + (size_t)gr * lda + k0 + chg * 8);
        }
#pragma unroll
        for (int s = 0; s < 2; ++s) {   // stage B: 512 chunks
            int c = s * 256 + t;
            int colr = c >> 3, ch = c & 7;
            int chg = ch ^ (colr & 7);
            Bs[c] = *(const s8v*)(Bt + (size_t)(col0 + colr) * K + k0 + chg * 8);
        }
        __syncthreads();
#pragma unroll
        for (int kk = 0; kk < 2; ++kk) {
            s8v bf[4], af[2];
#pragma unroll
            for (int cf = 0; cf < 4; ++cf) {
                int colr = cf * 16 + l15;
                bf[cf] = Bs[colr * 8 + ((kk * 4 + lq) ^ l7)];
            }
#pragma unroll
            for (int rf = 0; rf < 2; ++rf) {
                int row = wv * 32 + rf * 16 + l15;
                af[rf] = As[row * 8 + ((kk * 4 + lq) ^ l7)];
            }
#pragma unroll
            for (int rf = 0; rf < 2; ++rf)
#pragma unroll
                for (int cf = 0; cf < 4; ++cf)
                    acc[rf][cf] = __builtin_amdgcn_mfma_f32_16x16x32_bf16(
                        af[rf], bf[cf], acc[rf][cf], 0, 0, 0);
        }
        __syncthreads();
    }
    // epilogue: D row = (lane>>4)*4 + r, col = lane&15 (within 16x16 frag)
#pragma unroll
    for (int rf = 0; rf < 2; ++rf) {
#pragma unroll
        for (int r = 0; r < 4; ++r) {
            int row = row0 + wv * 32 + rf * 16 + lq * 4 + r;
            if (row >= M) continue;
#pragma unroll
            for (int cf = 0; cf < 4; ++cf) {
                int colg = col0 + cf * 16 + l15;
                float v = acc[rf][cf][r];
                if (bias) v += bias[colg];
                if (OUT_BF16)
                    ((unsigned short*)Cout)[(size_t)row * ldc + colg] = f2b(v);
                else
                    ((float*)Cout)[(size_t)row * ldc + colg] = v;
            }
        }
    }
}

// ---------------- gather aggregation (bf16 feat): out = di*sum(dj*feat_j) + di^2*feat_i (+b)(relu) ----------------
template <bool RELU, bool BIAS>
__global__ __launch_bounds__(256) void k_gather_b(
    const unsigned short* __restrict__ feat, const int* __restrict__ rowptr,
    const int* __restrict__ col, const float* __restrict__ dinv,
    const float* __restrict__ bias, unsigned short* __restrict__ out, int n)
{
    int wid  = (blockIdx.x * 256 + threadIdx.x) >> 6;
    int lane = threadIdx.x & 63;
    if (wid >= n) return;
    float di = dinv[wid];
    int p0 = rowptr[wid], p1 = rowptr[wid + 1];
    int deg = p1 - p0;
    // preload up to 64 neighbor ids + norms, broadcast via shuffle
    int myc = 0; float mydj = 0.f;
    if (lane < deg) { myc = col[p0 + lane]; mydj = dinv[myc]; }
    float4 acc = make_float4(0.f, 0.f, 0.f, 0.f);
    int dmin = deg < 64 ? deg : 64;
#pragma unroll 2
    for (int q = 0; q < dmin; ++q) {
        int j = __shfl(myc, q);
        float dj = __shfl(mydj, q);
        ushort4 v = *(const ushort4*)(feat + (size_t)j * HIDC + lane * 4);
        acc.x += dj * b2f(v.x); acc.y += dj * b2f(v.y);
        acc.z += dj * b2f(v.z); acc.w += dj * b2f(v.w);
    }
    for (int p = p0 + 64; p < p1; ++p) {  // rare tail (deg>64)
        int j = col[p];
        float dj = dinv[j];
        ushort4 v = *(const ushort4*)(feat + (size_t)j * HIDC + lane * 4);
        acc.x += dj * b2f(v.x); acc.y += dj * b2f(v.y);
        acc.z += dj * b2f(v.z); acc.w += dj * b2f(v.w);
    }
    ushort4 sv = *(const ushort4*)(feat + (size_t)wid * HIDC + lane * 4);
    float dd = di * di;
    float4 r;
    r.x = di * acc.x + dd * b2f(sv.x);
    r.y = di * acc.y + dd * b2f(sv.y);
    r.z = di * acc.z + dd * b2f(sv.z);
    r.w = di * acc.w + dd * b2f(sv.w);
    if (BIAS) {
        const float4 b = *(const float4*)(bias + lane * 4);
        r.x += b.x; r.y += b.y; r.z += b.z; r.w += b.w;
    }
    if (RELU) {
        r.x = fmaxf(r.x, 0.f); r.y = fmaxf(r.y, 0.f);
        r.z = fmaxf(r.z, 0.f); r.w = fmaxf(r.w, 0.f);
    }
    ushort4 o;
    o.x = f2b(r.x); o.y = f2b(r.y); o.z = f2b(r.z); o.w = f2b(r.w);
    *(ushort4*)(out + (size_t)wid * HIDC + lane * 4) = o;
}

// ---------------- small heads: softmax(g @ Wc + bc), g rows bf16 in gbb ----------------
template <int NC, int OFF>
__global__ void k_head_small(const unsigned short* __restrict__ gbb, const float* __restrict__ Wc,
                             const float* __restrict__ bc, float* __restrict__ out, int n)
{
    int wid  = (blockIdx.x * blockDim.x + threadIdx.x) >> 6;
    int lane = threadIdx.x & 63;
    if (wid >= n) return;
    const unsigned short* row = gbb + (size_t)wid * GT + OFF;
    float rv = (lane < NC) ? b2f(row[lane]) : 0.f;
    float logit = (lane < NC) ? bc[lane] : -INFINITY;
#pragma unroll
    for (int k = 0; k < NC; ++k) {
        float a = __shfl(rv, k);
        if (lane < NC) logit += a * Wc[k * NC + lane];
    }
    float m = logit;
    for (int off = 32; off; off >>= 1) m = fmaxf(m, __shfl_xor(m, off));
    float e = (lane < NC) ? __expf(logit - m) : 0.f;
    float s = e;
    for (int off = 32; off; off >>= 1) s += __shfl_xor(s, off);
    if (lane < NC) out[(size_t)wid * NC + lane] = e / s;
}

// ---------------- author softmax over fp32 logits [NN][384] (cols 0..349) ----------------
__global__ __launch_bounds__(256) void k_softmax350(const float* __restrict__ lg,
                                                    float* __restrict__ out, int n)
{
    int wid  = (blockIdx.x * 256 + threadIdx.x) >> 6;
    int lane = threadIdx.x & 63;
    if (wid >= n) return;
    const float* row = lg + (size_t)wid * 384;
    float v[6];
    float m = -INFINITY;
#pragma unroll
    for (int i = 0; i < 6; ++i) {
        int c = lane + 64 * i;
        v[i] = (c < 350) ? row[c] : -INFINITY;
        m = fmaxf(m, v[i]);
    }
    for (int off = 32; off; off >>= 1) m = fmaxf(m, __shfl_xor(m, off));
    float s = 0.f;
#pragma unroll
    for (int i = 0; i < 6; ++i) {
        int c = lane + 64 * i;
        v[i] = (c < 350) ? __expf(v[i] - m) : 0.f;
        s += v[i];
    }
    for (int off = 32; off; off >>= 1) s += __shfl_xor(s, off);
    float inv = 1.f / s;
#pragma unroll
    for (int i = 0; i < 6; ++i) {
        int c = lane + 64 * i;
        if (c < 350) out[(size_t)wid * 350 + c] = v[i] * inv;
    }
}

// ---------------- launch ----------------
extern "C" void kernel_launch(void* const* d_in, const int* in_sizes, int n_in,
                              void* d_out, int out_size, void* d_ws, size_t ws_size,
                              hipStream_t stream)
{
    const float* x   = (const float*)d_in[0];
    const int*   ei  = (const int*)d_in[1];
    const float* W1  = (const float*)d_in[2];
    const float* b1  = (const float*)d_in[3];
    const float* Wg0 = (const float*)d_in[4];
    const float* bg0 = (const float*)d_in[5];
    const float* Wc0 = (const float*)d_in[6];
    const float* bc0 = (const float*)d_in[7];
    const float* Wg1 = (const float*)d_in[8];
    const float* bg1 = (const float*)d_in[9];
    const float* Wc1 = (const float*)d_in[10];
    const float* bc1 = (const float*)d_in[11];
    const float* Wg2 = (const float*)d_in[12];
    const float* bg2 = (const float*)d_in[13];
    const float* Wc2 = (const float*)d_in[14];
    const float* bc2 = (const float*)d_in[15];
    const float* Wg3 = (const float*)d_in[16];
    const float* bg3 = (const float*)d_in[17];
    const float* Wc3 = (const float*)d_in[18];
    const float* bc3 = (const float*)d_in[19];
    const int* srcI = ei;
    const int* dstI = ei + NE;

    char* ws = (char*)d_ws;
    size_t off = 0;
    auto alloc = [&](size_t bytes) { void* p = ws + off; off += (bytes + 255) & ~(size_t)255; return p; };
    float* dinv   = (float*)alloc(50176 * 4);
    int*   rowptr = (int*)  alloc(50432 * 4);
    int*   cnt    = (int*)  alloc(2 * 50176 * 4);   // cnt + cursor contiguous
    int*   cursor = cnt + 50176;
    int*   bsum   = (int*)  alloc(1024);
    int*   bsumx  = (int*)  alloc(1024);
    int*   col    = (int*)  alloc((size_t)NE * 4);
    unsigned short* W1t   = (unsigned short*)alloc(256 * 512 * 2);
    unsigned short* Wallt = (unsigned short*)alloc(448 * 256 * 2);
    float*          ballp = (float*)alloc(448 * 4);
    unsigned short* Wc3t  = (unsigned short*)alloc(384 * 384 * 2);
    float*          bc3p  = (float*)alloc(384 * 4);
    unsigned short* xb  = (unsigned short*)alloc((size_t)NN * INC * 2);   // 51.2MB (region B)
    unsigned short* xwb = (unsigned short*)alloc((size_t)NN * HIDC * 2);  // 25.6MB (region C)
    unsigned short* hb  = (unsigned short*)alloc((size_t)NN * HIDC * 2);  // region D
    unsigned short* gbb = (unsigned short*)alloc((size_t)NN * GT * 2);    // region F
    float* lgb = (float*)xb;           // alias B+C (needs 76.8MB = 51.2 + 25.6, contiguous)
    unsigned short* ahb = xwb;         // alias C (xwb dead after gather1)

    float* out0 = (float*)d_out;                     // type  [NN][10]
    float* out1 = out0 + (size_t)NN * 10;            // school[NN][25]
    float* out2 = out1 + (size_t)NN * 25;            // time  [NN][16]
    float* out3 = out2 + (size_t)NN * 16;            // author[NN][350]

    // ---- CSR build ----
    k_zero_i<<<(2 * 50176 + 255) / 256, 256, 0, stream>>>(cnt, 2 * 50176);
    k_deg_count<<<(NE + 255) / 256, 256, 0, stream>>>(dstI, cnt, NE);
    k_dinv<<<NBLK, 256, 0, stream>>>(cnt, dinv, NN);
    k_scan1<<<NBLK, 256, 0, stream>>>(cnt, rowptr, bsum, NN);
    k_scan2<<<1, 256, 0, stream>>>(bsum, bsumx, NBLK);
    k_scan3<<<NBLK, 256, 0, stream>>>(rowptr, bsumx, NN, NE);
    k_fill<<<(NE + 255) / 256, 256, 0, stream>>>(srcI, dstI, rowptr, cursor, col, NE);

    // ---- converts / packs ----
    k_f2b<<<(NN * INC / 4 + 255) / 256, 256, 0, stream>>>(x, xb, NN * INC / 4);
    k_packW1t<<<(256 * 512 + 255) / 256, 256, 0, stream>>>(W1, W1t);
    k_packWall<<<(448 * 256 + 255) / 256, 256, 0, stream>>>(Wg0, Wg1, Wg2, Wg3, bg0, bg1, bg2, bg3, Wallt, ballp);
    k_packWc3<<<(384 * 384 + 255) / 256, 256, 0, stream>>>(Wc3, bc3, Wc3t, bc3p);

    const int MT = (NN + 127) / 128;  // 391 row tiles

    // ---- layer 1: xw = x@W1 (bf16) ; h = relu(gather(xw) + b1) (bf16) ----
    mfma_gemm<true><<<dim3(HIDC / 64, MT), 256, 0, stream>>>(xb, W1t, xwb, nullptr, NN, INC, INC, HIDC);
    k_gather_b<true, true><<<(NN + 3) / 4, 256, 0, stream>>>(xwb, rowptr, col, dinv, b1, hb, NN);

    // ---- heads: ah = gather(h) ; g_all = ah @ Wall + ball (bf16) ----
    k_gather_b<false, false><<<(NN + 3) / 4, 256, 0, stream>>>(hb, rowptr, col, dinv, nullptr, ahb, NN);
    mfma_gemm<true><<<dim3(GT / 64, MT), 256, 0, stream>>>(ahb, Wallt, gbb, ballp, NN, HIDC, HIDC, GT);

    // ---- author: logits = g_author @ Wc3 + bc3 (MFMA, fp32 out), then softmax ----
    mfma_gemm<false><<<dim3(384 / 64, MT), 256, 0, stream>>>(gbb, Wc3t, lgb, bc3p, NN, 384, GT, 384);

    // ---- small heads (read gbb bf16) ----
    k_head_small<10, 352><<<(NN + 3) / 4, 256, 0, stream>>>(gbb, Wc0, bc0, out0, NN);
    k_head_small<25, 362><<<(NN + 3) / 4, 256, 0, stream>>>(gbb, Wc1, bc1, out1, NN);
    k_head_small<16, 387><<<(NN + 3) / 4, 256, 0, stream>>>(gbb, Wc2, bc2, out2, NN);
    k_softmax350<<<(NN + 3) / 4, 256, 0, stream>>>(lgb, out3, NN);
}

// Round 4
// 357.484 us; speedup vs baseline: 14.1747x; 1.3823x over previous
//
#include <hip/hip_runtime.h>
#include <hip/hip_bf16.h>
#include <cstdint>
#include <cstddef>
#include <math.h>

#define NN 50000
#define NE 800000
#define INC 512
#define HIDC 256
#define NBLK ((NN + 255) / 256)

typedef __attribute__((ext_vector_type(8))) short s8v;   // 8 bf16 = 4 VGPR
typedef __attribute__((ext_vector_type(4))) float f4v;

__device__ __forceinline__ float b2f(unsigned short u) {
    return __uint_as_float(((unsigned)u) << 16);
}
__device__ __forceinline__ unsigned short f2b(float f) {
    __hip_bfloat16 h = __float2bfloat16(f);
    return *reinterpret_cast<unsigned short*>(&h);
}

// ---------------- CSR build ----------------
__global__ void k_zero_i(int* a, int n) {
    int i = blockIdx.x * 256 + threadIdx.x;
    if (i < n) a[i] = 0;
}
__global__ void k_deg_count(const int* __restrict__ dst, int* __restrict__ cnt, int e) {
    int i = blockIdx.x * 256 + threadIdx.x;
    if (i < e) atomicAdd(&cnt[dst[i]], 1);
}
__global__ void k_dinv(const int* __restrict__ cnt, float* __restrict__ dinv, int n) {
    int i = blockIdx.x * 256 + threadIdx.x;
    if (i < n) dinv[i] = rsqrtf((float)cnt[i] + 1.0f);
}
__global__ void k_scan1(const int* __restrict__ cnt, int* __restrict__ excl,
                        int* __restrict__ bsum, int n) {
    __shared__ int s[256];
    int i = blockIdx.x * 256 + threadIdx.x;
    int v = (i < n) ? cnt[i] : 0;
    s[threadIdx.x] = v;
    __syncthreads();
    for (int off = 1; off < 256; off <<= 1) {
        int t = (threadIdx.x >= off) ? s[threadIdx.x - off] : 0;
        __syncthreads();
        s[threadIdx.x] += t;
        __syncthreads();
    }
    if (i < n) excl[i] = s[threadIdx.x] - v;
    if (threadIdx.x == 255) bsum[blockIdx.x] = s[255];
}
__global__ void k_scan2(int* __restrict__ bsum, int* __restrict__ bsumx, int nb) {
    __shared__ int s[256];
    int t = threadIdx.x;
    int v = (t < nb) ? bsum[t] : 0;
    s[t] = v;
    __syncthreads();
    for (int off = 1; off < 256; off <<= 1) {
        int tt = (t >= off) ? s[t - off] : 0;
        __syncthreads();
        s[t] += tt;
        __syncthreads();
    }
    if (t < nb) bsumx[t] = s[t] - v;
}
__global__ void k_scan3(int* __restrict__ rowptr, const int* __restrict__ bsumx, int n, int e) {
    int i = blockIdx.x * 256 + threadIdx.x;
    if (i < n) rowptr[i] += bsumx[blockIdx.x];
    if (i == 0) rowptr[n] = e;
}
__global__ void k_fill(const int* __restrict__ src, const int* __restrict__ dst,
                       const int* __restrict__ rowptr, int* __restrict__ cursor,
                       int* __restrict__ col, int e) {
    int i = blockIdx.x * 256 + threadIdx.x;
    if (i >= e) return;
    int d = dst[i];
    int pos = rowptr[d] + atomicAdd(&cursor[d], 1);
    col[pos] = src[i];
}

// ---------------- weight prep ----------------
// W1t[c][k] = bf16(W1[k][c]) : Bt layout for gemm1
__global__ void k_packW1t(const float* __restrict__ W1, unsigned short* __restrict__ W1t) {
    int t = blockIdx.x * 256 + threadIdx.x;  // 256*512
    if (t >= 256 * 512) return;
    int c = t >> 9, k = t & 511;
    W1t[t] = f2b(W1[(size_t)k * 256 + c]);
}
// transpose W[256][nc] -> Wt[nc][256]
__global__ void k_tr(const float* __restrict__ W, float* __restrict__ Wt, int nc) {
    int t = blockIdx.x * 256 + threadIdx.x;
    if (t >= 256 * nc) return;
    int k = t / nc, i = t - k * nc;
    Wt[i * 256 + k] = W[t];
}
// folded weights Wft[j][k] = bf16( sum_i Wg[k][i] * Wc[i][j] ), packed cols:
// author j=0..349 | pad 350..351 | type 352..361 | school 362..386 | time 387..402 | pad..447
__global__ void k_fold(const float* __restrict__ Wgt3, const float* __restrict__ Wc3,
                       const float* __restrict__ Wgt0, const float* __restrict__ Wc0,
                       const float* __restrict__ Wgt1, const float* __restrict__ Wc1,
                       const float* __restrict__ Wgt2, const float* __restrict__ Wc2,
                       unsigned short* __restrict__ Wft) {
    int t = blockIdx.x * 256 + threadIdx.x;  // t = j*256 + k
    if (t >= 448 * 256) return;
    int j = t >> 8, k = t & 255;
    float s = 0.f;
    if (j < 350)              { for (int i = 0; i < 350; ++i) s += Wgt3[i * 256 + k] * Wc3[(size_t)i * 350 + j]; }
    else if (j >= 352 && j < 362) { int jj = j - 352; for (int i = 0; i < 10; ++i) s += Wgt0[i * 256 + k] * Wc0[i * 10 + jj]; }
    else if (j >= 362 && j < 387) { int jj = j - 362; for (int i = 0; i < 25; ++i) s += Wgt1[i * 256 + k] * Wc1[i * 25 + jj]; }
    else if (j >= 387 && j < 403) { int jj = j - 387; for (int i = 0; i < 16; ++i) s += Wgt2[i * 256 + k] * Wc2[i * 16 + jj]; }
    Wft[t] = f2b(s);
}
// folded bias bfv[j] = bc[j'] + sum_i bg[i]*Wc[i][j']
__global__ void k_foldb(const float* __restrict__ bg3, const float* __restrict__ bc3, const float* __restrict__ Wc3,
                        const float* __restrict__ bg0, const float* __restrict__ bc0, const float* __restrict__ Wc0,
                        const float* __restrict__ bg1, const float* __restrict__ bc1, const float* __restrict__ Wc1,
                        const float* __restrict__ bg2, const float* __restrict__ bc2, const float* __restrict__ Wc2,
                        float* __restrict__ bfv) {
    int j = blockIdx.x * 64 + threadIdx.x;
    if (j >= 448) return;
    float s = 0.f;
    if (j < 350)              { s = bc3[j]; for (int i = 0; i < 350; ++i) s += bg3[i] * Wc3[(size_t)i * 350 + j]; }
    else if (j >= 352 && j < 362) { int jj = j - 352; s = bc0[jj]; for (int i = 0; i < 10; ++i) s += bg0[i] * Wc0[i * 10 + jj]; }
    else if (j >= 362 && j < 387) { int jj = j - 362; s = bc1[jj]; for (int i = 0; i < 25; ++i) s += bg1[i] * Wc1[i * 25 + jj]; }
    else if (j >= 387 && j < 403) { int jj = j - 387; s = bc2[jj]; for (int i = 0; i < 16; ++i) s += bg2[i] * Wc2[i * 16 + jj]; }
    bfv[j] = s;
}

// ---------------- gemm1: xwb = bf16( fp32 X [M][512] @ W1t ) , BM=64, BN=256, 256 thr ----------------
__global__ __launch_bounds__(256) void gemm1_conv(
    const float* __restrict__ X, const unsigned short* __restrict__ Bt,
    unsigned short* __restrict__ C, int M)
{
    __shared__ s8v As[512];    // 64 rows x 8 chunks, XOR-swizzled
    __shared__ s8v Bs[2048];   // 256 cols x 8 chunks
    const int t = threadIdx.x;
    const int lane = t & 63, wv = t >> 6;
    const int row0 = blockIdx.x * 64;
    const int l15 = lane & 15, lq = lane >> 4, l7 = lane & 7;

    f4v acc[16] = {};
    for (int k0 = 0; k0 < 512; k0 += 64) {
#pragma unroll
        for (int s = 0; s < 2; ++s) {   // A: 512 chunks, fp32->bf16 in regs
            int c = s * 256 + t;
            int row = c >> 3, ch = c & 7;
            int chg = ch ^ (row & 7);
            int gr = row0 + row; if (gr >= M) gr = M - 1;
            const float* src = X + (size_t)gr * 512 + k0 + chg * 8;
            float4 a = *(const float4*)src;
            float4 b = *(const float4*)(src + 4);
            s8v o;
            o[0] = (short)f2b(a.x); o[1] = (short)f2b(a.y);
            o[2] = (short)f2b(a.z); o[3] = (short)f2b(a.w);
            o[4] = (short)f2b(b.x); o[5] = (short)f2b(b.y);
            o[6] = (short)f2b(b.z); o[7] = (short)f2b(b.w);
            As[c] = o;
        }
#pragma unroll
        for (int s = 0; s < 8; ++s) {   // B: 2048 chunks
            int c = s * 256 + t;
            int colr = c >> 3, ch = c & 7;
            int chg = ch ^ (colr & 7);
            Bs[c] = *(const s8v*)(Bt + (size_t)colr * 512 + k0 + chg * 8);
        }
        __syncthreads();
#pragma unroll
        for (int kk = 0; kk < 2; ++kk) {
            s8v af = As[(wv * 16 + l15) * 8 + ((kk * 4 + lq) ^ l7)];
#pragma unroll
            for (int cf = 0; cf < 16; ++cf) {
                s8v bfr = Bs[(cf * 16 + l15) * 8 + ((kk * 4 + lq) ^ l7)];
                acc[cf] = __builtin_amdgcn_mfma_f32_16x16x32_bf16(af, bfr, acc[cf], 0, 0, 0);
            }
        }
        __syncthreads();
    }
#pragma unroll
    for (int cf = 0; cf < 16; ++cf)
#pragma unroll
        for (int r = 0; r < 4; ++r) {
            int row = row0 + wv * 16 + lq * 4 + r;
            if (row < M) C[(size_t)row * 256 + cf * 16 + l15] = f2b(acc[cf][r]);
        }
}

// ---------------- gather: 2 nodes/wave, 32 lanes x ushort8 per row ----------------
template <bool RELU, bool BIAS>
__global__ __launch_bounds__(256) void k_gather2(
    const unsigned short* __restrict__ feat, const int* __restrict__ rowptr,
    const int* __restrict__ col, const float* __restrict__ dinv,
    const float* __restrict__ bias, unsigned short* __restrict__ out, int n)
{
    int unit = (blockIdx.x * 256 + threadIdx.x) >> 5;   // node id
    int l32 = threadIdx.x & 31;
    if (unit >= n) return;
    float di = dinv[unit];
    int p0 = rowptr[unit], p1 = rowptr[unit + 1];
    int deg = p1 - p0;
    int myc = 0; float mydj = 0.f;
    if (l32 < deg) { myc = col[p0 + l32]; mydj = dinv[myc]; }
    float acc[8] = {};
    int dmin = deg < 32 ? deg : 32;
    int base = threadIdx.x & 32;
#pragma unroll 2
    for (int q = 0; q < dmin; ++q) {
        int j = __shfl(myc, base + q);
        float dj = __shfl(mydj, base + q);
        s8v v = *(const s8v*)(feat + (size_t)j * HIDC + l32 * 8);
#pragma unroll
        for (int c = 0; c < 8; ++c) acc[c] += dj * b2f((unsigned short)v[c]);
    }
    for (int p = p0 + 32; p < p1; ++p) {   // rare tail (deg > 32)
        int j = col[p];
        float dj = dinv[j];
        s8v v = *(const s8v*)(feat + (size_t)j * HIDC + l32 * 8);
#pragma unroll
        for (int c = 0; c < 8; ++c) acc[c] += dj * b2f((unsigned short)v[c]);
    }
    s8v sv = *(const s8v*)(feat + (size_t)unit * HIDC + l32 * 8);
    float dd = di * di;
    s8v o;
#pragma unroll
    for (int c = 0; c < 8; ++c) {
        float r = di * acc[c] + dd * b2f((unsigned short)sv[c]);
        if (BIAS) r += bias[l32 * 8 + c];
        if (RELU) r = fmaxf(r, 0.f);
        o[c] = (short)f2b(r);
    }
    *(s8v*)(out + (size_t)unit * HIDC + l32 * 8) = o;
}

// ---------------- gemm2 + 4-head softmax: logits = ahb @ Wft + bfv -> softmax -> d_out ----------------
// BM=64, BN=448, 256 thr (4 waves x 16 rows), acc[28]
__global__ __launch_bounds__(256) void gemm2_heads(
    const unsigned short* __restrict__ A, const unsigned short* __restrict__ Bt,
    const float* __restrict__ bfv,
    float* __restrict__ o0, float* __restrict__ o1,
    float* __restrict__ o2, float* __restrict__ o3, int M)
{
    __shared__ s8v As[512];    // 64 x 8
    __shared__ s8v Bs[3584];   // 448 x 8
    const int t = threadIdx.x;
    const int lane = t & 63, wv = t >> 6;
    const int row0 = blockIdx.x * 64;
    const int l15 = lane & 15, lq = lane >> 4, l7 = lane & 7;

    f4v acc[28] = {};
    for (int k0 = 0; k0 < 256; k0 += 64) {
#pragma unroll
        for (int s = 0; s < 2; ++s) {
            int c = s * 256 + t;
            int row = c >> 3, ch = c & 7;
            int chg = ch ^ (row & 7);
            int gr = row0 + row; if (gr >= M) gr = M - 1;
            As[c] = *(const s8v*)(A + (size_t)gr * 256 + k0 + chg * 8);
        }
#pragma unroll
        for (int s = 0; s < 14; ++s) {
            int c = s * 256 + t;
            int colr = c >> 3, ch = c & 7;
            int chg = ch ^ (colr & 7);
            Bs[c] = *(const s8v*)(Bt + (size_t)colr * 256 + k0 + chg * 8);
        }
        __syncthreads();
#pragma unroll
        for (int kk = 0; kk < 2; ++kk) {
            s8v af = As[(wv * 16 + l15) * 8 + ((kk * 4 + lq) ^ l7)];
#pragma unroll
            for (int cf = 0; cf < 28; ++cf) {
                s8v bfr = Bs[(cf * 16 + l15) * 8 + ((kk * 4 + lq) ^ l7)];
                acc[cf] = __builtin_amdgcn_mfma_f32_16x16x32_bf16(af, bfr, acc[cf], 0, 0, 0);
            }
        }
        __syncthreads();
    }
    // fold bias in
#pragma unroll
    for (int cf = 0; cf < 28; ++cf) {
        float b = bfv[cf * 16 + l15];
#pragma unroll
        for (int r = 0; r < 4; ++r) acc[cf][r] += b;
    }
    // per-row 4-head segmented softmax; row r of frag held by 16 lanes (lq group)
#pragma unroll
    for (int r = 0; r < 4; ++r) {
        int row = row0 + wv * 16 + lq * 4 + r;
        float m0 = -1e30f, m1 = -1e30f, m2 = -1e30f, m3 = -1e30f;
#pragma unroll
        for (int cf = 0; cf < 28; ++cf) {
            int colc = cf * 16 + l15;
            float xv = acc[cf][r];
            if (colc < 350) m0 = fmaxf(m0, xv);
            else if (colc >= 352 && colc < 362) m1 = fmaxf(m1, xv);
            else if (colc >= 362 && colc < 387) m2 = fmaxf(m2, xv);
            else if (colc >= 387 && colc < 403) m3 = fmaxf(m3, xv);
        }
#pragma unroll
        for (int o = 8; o; o >>= 1) {
            m0 = fmaxf(m0, __shfl_xor(m0, o));
            m1 = fmaxf(m1, __shfl_xor(m1, o));
            m2 = fmaxf(m2, __shfl_xor(m2, o));
            m3 = fmaxf(m3, __shfl_xor(m3, o));
        }
        float s0 = 0.f, s1 = 0.f, s2 = 0.f, s3 = 0.f;
#pragma unroll
        for (int cf = 0; cf < 28; ++cf) {
            int colc = cf * 16 + l15;
            float xv = acc[cf][r];
            float e = 0.f;
            if (colc < 350)                     { e = __expf(xv - m0); s0 += e; }
            else if (colc >= 352 && colc < 362) { e = __expf(xv - m1); s1 += e; }
            else if (colc >= 362 && colc < 387) { e = __expf(xv - m2); s2 += e; }
            else if (colc >= 387 && colc < 403) { e = __expf(xv - m3); s3 += e; }
            acc[cf][r] = e;
        }
#pragma unroll
        for (int o = 8; o; o >>= 1) {
            s0 += __shfl_xor(s0, o); s1 += __shfl_xor(s1, o);
            s2 += __shfl_xor(s2, o); s3 += __shfl_xor(s3, o);
        }
        float i0 = 1.f / s0, i1 = 1.f / s1, i2 = 1.f / s2, i3 = 1.f / s3;
        if (row < M) {
#pragma unroll
            for (int cf = 0; cf < 28; ++cf) {
                int colc = cf * 16 + l15;
                float e = acc[cf][r];
                if (colc < 350)                     o3[(size_t)row * 350 + colc]       = e * i0;
                else if (colc >= 352 && colc < 362) o0[(size_t)row * 10 + colc - 352]  = e * i1;
                else if (colc >= 362 && colc < 387) o1[(size_t)row * 25 + colc - 362]  = e * i2;
                else if (colc >= 387 && colc < 403) o2[(size_t)row * 16 + colc - 387]  = e * i3;
            }
        }
    }
}

// ---------------- launch ----------------
extern "C" void kernel_launch(void* const* d_in, const int* in_sizes, int n_in,
                              void* d_out, int out_size, void* d_ws, size_t ws_size,
                              hipStream_t stream)
{
    const float* x   = (const float*)d_in[0];
    const int*   ei  = (const int*)d_in[1];
    const float* W1  = (const float*)d_in[2];
    const float* b1  = (const float*)d_in[3];
    const float* Wg0 = (const float*)d_in[4];
    const float* bg0 = (const float*)d_in[5];
    const float* Wc0 = (const float*)d_in[6];
    const float* bc0 = (const float*)d_in[7];
    const float* Wg1 = (const float*)d_in[8];
    const float* bg1 = (const float*)d_in[9];
    const float* Wc1 = (const float*)d_in[10];
    const float* bc1 = (const float*)d_in[11];
    const float* Wg2 = (const float*)d_in[12];
    const float* bg2 = (const float*)d_in[13];
    const float* Wc2 = (const float*)d_in[14];
    const float* bc2 = (const float*)d_in[15];
    const float* Wg3 = (const float*)d_in[16];
    const float* bg3 = (const float*)d_in[17];
    const float* Wc3 = (const float*)d_in[18];
    const float* bc3 = (const float*)d_in[19];
    const int* srcI = ei;
    const int* dstI = ei + NE;

    char* ws = (char*)d_ws;
    size_t off = 0;
    auto alloc = [&](size_t bytes) { void* p = ws + off; off += (bytes + 255) & ~(size_t)255; return p; };
    float* dinv   = (float*)alloc(50176 * 4);
    int*   rowptr = (int*)  alloc(50432 * 4);
    int*   cnt    = (int*)  alloc(2 * 50176 * 4);   // cnt + cursor contiguous
    int*   cursor = cnt + 50176;
    int*   bsum   = (int*)  alloc(1024);
    int*   bsumx  = (int*)  alloc(1024);
    int*   col    = (int*)  alloc((size_t)NE * 4);
    unsigned short* W1t = (unsigned short*)alloc(256 * 512 * 2);
    unsigned short* Wft = (unsigned short*)alloc(448 * 256 * 2);
    float* bfv   = (float*)alloc(448 * 4);
    float* Wgt3  = (float*)alloc(350 * 256 * 4);
    float* Wgt0  = (float*)alloc(10 * 256 * 4);
    float* Wgt1  = (float*)alloc(25 * 256 * 4);
    float* Wgt2  = (float*)alloc(16 * 256 * 4);
    unsigned short* xwb = (unsigned short*)alloc((size_t)NN * HIDC * 2);
    unsigned short* hb  = (unsigned short*)alloc((size_t)NN * HIDC * 2);
    unsigned short* ahb = xwb;   // alias: xwb dead after gather1

    float* out0 = (float*)d_out;                     // type  [NN][10]
    float* out1 = out0 + (size_t)NN * 10;            // school[NN][25]
    float* out2 = out1 + (size_t)NN * 25;            // time  [NN][16]
    float* out3 = out2 + (size_t)NN * 16;            // author[NN][350]

    // ---- CSR build ----
    k_zero_i<<<(2 * 50176 + 255) / 256, 256, 0, stream>>>(cnt, 2 * 50176);
    k_deg_count<<<(NE + 255) / 256, 256, 0, stream>>>(dstI, cnt, NE);
    k_dinv<<<NBLK, 256, 0, stream>>>(cnt, dinv, NN);
    k_scan1<<<NBLK, 256, 0, stream>>>(cnt, rowptr, bsum, NN);
    k_scan2<<<1, 256, 0, stream>>>(bsum, bsumx, NBLK);
    k_scan3<<<NBLK, 256, 0, stream>>>(rowptr, bsumx, NN, NE);
    k_fill<<<(NE + 255) / 256, 256, 0, stream>>>(srcI, dstI, rowptr, cursor, col, NE);

    // ---- weight prep ----
    k_packW1t<<<(256 * 512 + 255) / 256, 256, 0, stream>>>(W1, W1t);
    k_tr<<<350, 256, 0, stream>>>(Wg3, Wgt3, 350);
    k_tr<<<10, 256, 0, stream>>>(Wg0, Wgt0, 10);
    k_tr<<<25, 256, 0, stream>>>(Wg1, Wgt1, 25);
    k_tr<<<16, 256, 0, stream>>>(Wg2, Wgt2, 16);
    k_fold<<<448, 256, 0, stream>>>(Wgt3, Wc3, Wgt0, Wc0, Wgt1, Wc1, Wgt2, Wc2, Wft);
    k_foldb<<<7, 64, 0, stream>>>(bg3, bc3, Wc3, bg0, bc0, Wc0, bg1, bc1, Wc1, bg2, bc2, Wc2, bfv);

    // ---- pipeline ----
    gemm1_conv<<<(NN + 63) / 64, 256, 0, stream>>>(x, W1t, xwb, NN);
    k_gather2<true, true><<<(NN + 7) / 8, 256, 0, stream>>>(xwb, rowptr, col, dinv, b1, hb, NN);
    k_gather2<false, false><<<(NN + 7) / 8, 256, 0, stream>>>(hb, rowptr, col, dinv, nullptr, ahb, NN);
    gemm2_heads<<<(NN + 63) / 64, 256, 0, stream>>>(ahb, Wft, bfv, out0, out1, out2, out3, NN);
}

// Round 5
// 328.042 us; speedup vs baseline: 15.4470x; 1.0898x over previous
//
#include <hip/hip_runtime.h>
#include <hip/hip_bf16.h>
#include <cstdint>
#include <cstddef>
#include <math.h>

#define NN 50000
#define NE 800000
#define INC 512
#define HIDC 256
#define NBLK ((NN + 255) / 256)

typedef __attribute__((ext_vector_type(8))) short s8v;   // 8 bf16 = 4 VGPR
typedef __attribute__((ext_vector_type(4))) float f4v;

__device__ __forceinline__ float b2f(unsigned short u) {
    return __uint_as_float(((unsigned)u) << 16);
}
__device__ __forceinline__ unsigned short f2b(float f) {
    __hip_bfloat16 h = __float2bfloat16(f);
    return *reinterpret_cast<unsigned short*>(&h);
}

// ---------------- CSR build ----------------
__global__ void k_deg_count(const int* __restrict__ dst, int* __restrict__ cnt, int e) {
    int i = blockIdx.x * 256 + threadIdx.x;
    if (i < e) atomicAdd(&cnt[dst[i]], 1);
}
// scan1 + dinv fused
__global__ void k_scan1(const int* __restrict__ cnt, int* __restrict__ excl,
                        int* __restrict__ bsum, float* __restrict__ dinv, int n) {
    __shared__ int s[256];
    int i = blockIdx.x * 256 + threadIdx.x;
    int v = (i < n) ? cnt[i] : 0;
    if (i < n) dinv[i] = rsqrtf((float)v + 1.0f);
    s[threadIdx.x] = v;
    __syncthreads();
    for (int off = 1; off < 256; off <<= 1) {
        int t = (threadIdx.x >= off) ? s[threadIdx.x - off] : 0;
        __syncthreads();
        s[threadIdx.x] += t;
        __syncthreads();
    }
    if (i < n) excl[i] = s[threadIdx.x] - v;
    if (threadIdx.x == 255) bsum[blockIdx.x] = s[255];
}
__global__ void k_scan2(int* __restrict__ bsum, int* __restrict__ bsumx, int nb) {
    __shared__ int s[256];
    int t = threadIdx.x;
    int v = (t < nb) ? bsum[t] : 0;
    s[t] = v;
    __syncthreads();
    for (int off = 1; off < 256; off <<= 1) {
        int tt = (t >= off) ? s[t - off] : 0;
        __syncthreads();
        s[t] += tt;
        __syncthreads();
    }
    if (t < nb) bsumx[t] = s[t] - v;
}
__global__ void k_scan3(int* __restrict__ rowptr, const int* __restrict__ bsumx, int n, int e) {
    int i = blockIdx.x * 256 + threadIdx.x;
    if (i < n) rowptr[i] += bsumx[blockIdx.x];
    if (i == 0) rowptr[n] = e;
}
__global__ void k_fill(const int* __restrict__ src, const int* __restrict__ dst,
                       const int* __restrict__ rowptr, int* __restrict__ cursor,
                       int* __restrict__ col, int e) {
    int i = blockIdx.x * 256 + threadIdx.x;
    if (i >= e) return;
    int d = dst[i];
    int pos = rowptr[d] + atomicAdd(&cursor[d], 1);
    col[pos] = src[i];
}

// ---------------- fused weight prep: W1t | Wft (folded Wg@Wc) | bfv ----------------
// blocks 0..511: W1t ; 512..959: Wft col j=b-512 ; 960..961: bfv
__global__ void k_prep(const float* __restrict__ W1,
                       const float* __restrict__ Wg0, const float* __restrict__ Wc0,
                       const float* __restrict__ bg0, const float* __restrict__ bc0,
                       const float* __restrict__ Wg1, const float* __restrict__ Wc1,
                       const float* __restrict__ bg1, const float* __restrict__ bc1,
                       const float* __restrict__ Wg2, const float* __restrict__ Wc2,
                       const float* __restrict__ bg2, const float* __restrict__ bc2,
                       const float* __restrict__ Wg3, const float* __restrict__ Wc3,
                       const float* __restrict__ bg3, const float* __restrict__ bc3,
                       unsigned short* __restrict__ W1t, unsigned short* __restrict__ Wft,
                       float* __restrict__ bfv)
{
    int b = blockIdx.x, tid = threadIdx.x;
    if (b < 512) {
        int t = b * 256 + tid;           // 256*512 elems
        int c = t >> 9, k = t & 511;
        W1t[t] = f2b(W1[(size_t)k * 256 + c]);
    } else if (b < 960) {
        int j = b - 512, k = tid;
        float s = 0.f;
        if (j < 350)                  { for (int i = 0; i < 350; ++i) s += Wg3[k * 350 + i] * Wc3[(size_t)i * 350 + j]; }
        else if (j >= 352 && j < 362) { int jj = j - 352; for (int i = 0; i < 10; ++i) s += Wg0[k * 10 + i] * Wc0[i * 10 + jj]; }
        else if (j >= 362 && j < 387) { int jj = j - 362; for (int i = 0; i < 25; ++i) s += Wg1[k * 25 + i] * Wc1[i * 25 + jj]; }
        else if (j >= 387 && j < 403) { int jj = j - 387; for (int i = 0; i < 16; ++i) s += Wg2[k * 16 + i] * Wc2[i * 16 + jj]; }
        Wft[j * 256 + k] = f2b(s);
    } else {
        int j = (b - 960) * 256 + tid;
        if (j >= 448) return;
        float s = 0.f;
        if (j < 350)                  { s = bc3[j]; for (int i = 0; i < 350; ++i) s += bg3[i] * Wc3[(size_t)i * 350 + j]; }
        else if (j >= 352 && j < 362) { int jj = j - 352; s = bc0[jj]; for (int i = 0; i < 10; ++i) s += bg0[i] * Wc0[i * 10 + jj]; }
        else if (j >= 362 && j < 387) { int jj = j - 362; s = bc1[jj]; for (int i = 0; i < 25; ++i) s += bg1[i] * Wc1[i * 25 + jj]; }
        else if (j >= 387 && j < 403) { int jj = j - 387; s = bc2[jj]; for (int i = 0; i < 16; ++i) s += bg2[i] * Wc2[i * 16 + jj]; }
        bfv[j] = s;
    }
}

// ---------------- gemm1: xwb = bf16( fp32 X[M][512] @ W1t ), BM=64, BN=256, BK=32 ----------------
// LDS rows padded to 5 chunks (80B) -> <=2-way bank conflicts, no XOR needed.
__global__ __launch_bounds__(256) void gemm1_conv(
    const float* __restrict__ X, const unsigned short* __restrict__ Bt,
    unsigned short* __restrict__ C, int M)
{
    __shared__ s8v As[64 * 5];    // 64 rows x 4 chunks (stride 5)
    __shared__ s8v Bs[256 * 5];   // 256 cols x 4 chunks (stride 5)
    const int t = threadIdx.x;
    const int lane = t & 63, wv = t >> 6;
    const int row0 = blockIdx.x * 64;
    const int l15 = lane & 15, lq = lane >> 4;

    const int arow = t >> 2, ach = t & 3;           // A stage: 1 chunk/thread
    int gr = row0 + arow; if (gr >= M) gr = M - 1;
    const float* asrc = X + (size_t)gr * 512 + ach * 8;

    f4v acc[16] = {};
    for (int k0 = 0; k0 < 512; k0 += 32) {
        {
            float4 a = *(const float4*)(asrc + k0);
            float4 b = *(const float4*)(asrc + k0 + 4);
            s8v o;
            o[0] = (short)f2b(a.x); o[1] = (short)f2b(a.y);
            o[2] = (short)f2b(a.z); o[3] = (short)f2b(a.w);
            o[4] = (short)f2b(b.x); o[5] = (short)f2b(b.y);
            o[6] = (short)f2b(b.z); o[7] = (short)f2b(b.w);
            As[arow * 5 + ach] = o;
        }
#pragma unroll
        for (int s = 0; s < 4; ++s) {   // B: 1024 chunks
            int c = s * 256 + t;
            int colr = c >> 2, ch = c & 3;
            Bs[colr * 5 + ch] = *(const s8v*)(Bt + (size_t)colr * 512 + k0 + ch * 8);
        }
        __syncthreads();
        s8v af = As[(wv * 16 + l15) * 5 + lq];
#pragma unroll
        for (int cf = 0; cf < 16; ++cf) {
            s8v bfr = Bs[(cf * 16 + l15) * 5 + lq];
            acc[cf] = __builtin_amdgcn_mfma_f32_16x16x32_bf16(af, bfr, acc[cf], 0, 0, 0);
        }
        __syncthreads();
    }
#pragma unroll
    for (int cf = 0; cf < 16; ++cf)
#pragma unroll
        for (int r = 0; r < 4; ++r) {
            int row = row0 + wv * 16 + lq * 4 + r;
            if (row < M) C[(size_t)row * 256 + cf * 16 + l15] = f2b(acc[cf][r]);
        }
}

// ---------------- gather: 2 nodes/wave, 32 lanes x ushort8 per row ----------------
template <bool RELU, bool BIAS>
__global__ __launch_bounds__(256) void k_gather2(
    const unsigned short* __restrict__ feat, const int* __restrict__ rowptr,
    const int* __restrict__ col, const float* __restrict__ dinv,
    const float* __restrict__ bias, unsigned short* __restrict__ out, int n)
{
    int unit = (blockIdx.x * 256 + threadIdx.x) >> 5;   // node id
    int l32 = threadIdx.x & 31;
    if (unit >= n) return;
    float di = dinv[unit];
    int p0 = rowptr[unit], p1 = rowptr[unit + 1];
    int deg = p1 - p0;
    int myc = 0; float mydj = 0.f;
    if (l32 < deg) { myc = col[p0 + l32]; mydj = dinv[myc]; }
    float acc[8] = {};
    int dmin = deg < 32 ? deg : 32;
    int base = threadIdx.x & 32;
#pragma unroll 2
    for (int q = 0; q < dmin; ++q) {
        int j = __shfl(myc, base + q);
        float dj = __shfl(mydj, base + q);
        s8v v = *(const s8v*)(feat + (size_t)j * HIDC + l32 * 8);
#pragma unroll
        for (int c = 0; c < 8; ++c) acc[c] += dj * b2f((unsigned short)v[c]);
    }
    for (int p = p0 + 32; p < p1; ++p) {   // rare tail (deg > 32)
        int j = col[p];
        float dj = dinv[j];
        s8v v = *(const s8v*)(feat + (size_t)j * HIDC + l32 * 8);
#pragma unroll
        for (int c = 0; c < 8; ++c) acc[c] += dj * b2f((unsigned short)v[c]);
    }
    s8v sv = *(const s8v*)(feat + (size_t)unit * HIDC + l32 * 8);
    float dd = di * di;
    s8v o;
#pragma unroll
    for (int c = 0; c < 8; ++c) {
        float r = di * acc[c] + dd * b2f((unsigned short)sv[c]);
        if (BIAS) r += bias[l32 * 8 + c];
        if (RELU) r = fmaxf(r, 0.f);
        o[c] = (short)f2b(r);
    }
    *(s8v*)(out + (size_t)unit * HIDC + l32 * 8) = o;
}

// ---------------- gemm2 + 4-head softmax: BM=64, BN=448, BK=32 ----------------
__global__ __launch_bounds__(256) void gemm2_heads(
    const unsigned short* __restrict__ A, const unsigned short* __restrict__ Bt,
    const float* __restrict__ bfv,
    float* __restrict__ o0, float* __restrict__ o1,
    float* __restrict__ o2, float* __restrict__ o3, int M)
{
    __shared__ s8v As[64 * 5];    // 64 rows x 4 chunks (stride 5)
    __shared__ s8v Bs[448 * 5];   // 448 cols x 4 chunks (stride 5)
    const int t = threadIdx.x;
    const int lane = t & 63, wv = t >> 6;
    const int row0 = blockIdx.x * 64;
    const int l15 = lane & 15, lq = lane >> 4;

    const int arow = t >> 2, ach = t & 3;
    int gr = row0 + arow; if (gr >= M) gr = M - 1;
    const unsigned short* asrc = A + (size_t)gr * 256 + ach * 8;

    f4v acc[28] = {};
    for (int k0 = 0; k0 < 256; k0 += 32) {
        As[arow * 5 + ach] = *(const s8v*)(asrc + k0);
#pragma unroll
        for (int s = 0; s < 7; ++s) {   // B: 1792 chunks
            int c = s * 256 + t;
            int colr = c >> 2, ch = c & 3;
            Bs[colr * 5 + ch] = *(const s8v*)(Bt + (size_t)colr * 256 + k0 + ch * 8);
        }
        __syncthreads();
        s8v af = As[(wv * 16 + l15) * 5 + lq];
#pragma unroll
        for (int cf = 0; cf < 28; ++cf) {
            s8v bfr = Bs[(cf * 16 + l15) * 5 + lq];
            acc[cf] = __builtin_amdgcn_mfma_f32_16x16x32_bf16(af, bfr, acc[cf], 0, 0, 0);
        }
        __syncthreads();
    }
    // bias
#pragma unroll
    for (int cf = 0; cf < 28; ++cf) {
        float b = bfv[cf * 16 + l15];
#pragma unroll
        for (int r = 0; r < 4; ++r) acc[cf][r] += b;
    }
    // per-row 4-head segmented softmax (16 lanes per row)
#pragma unroll
    for (int r = 0; r < 4; ++r) {
        int row = row0 + wv * 16 + lq * 4 + r;
        float m0 = -1e30f, m1 = -1e30f, m2 = -1e30f, m3 = -1e30f;
#pragma unroll
        for (int cf = 0; cf < 28; ++cf) {
            int colc = cf * 16 + l15;
            float xv = acc[cf][r];
            if (colc < 350) m0 = fmaxf(m0, xv);
            else if (colc >= 352 && colc < 362) m1 = fmaxf(m1, xv);
            else if (colc >= 362 && colc < 387) m2 = fmaxf(m2, xv);
            else if (colc >= 387 && colc < 403) m3 = fmaxf(m3, xv);
        }
#pragma unroll
        for (int o = 8; o; o >>= 1) {
            m0 = fmaxf(m0, __shfl_xor(m0, o));
            m1 = fmaxf(m1, __shfl_xor(m1, o));
            m2 = fmaxf(m2, __shfl_xor(m2, o));
            m3 = fmaxf(m3, __shfl_xor(m3, o));
        }
        float s0 = 0.f, s1 = 0.f, s2 = 0.f, s3 = 0.f;
#pragma unroll
        for (int cf = 0; cf < 28; ++cf) {
            int colc = cf * 16 + l15;
            float xv = acc[cf][r];
            float e = 0.f;
            if (colc < 350)                     { e = __expf(xv - m0); s0 += e; }
            else if (colc >= 352 && colc < 362) { e = __expf(xv - m1); s1 += e; }
            else if (colc >= 362 && colc < 387) { e = __expf(xv - m2); s2 += e; }
            else if (colc >= 387 && colc < 403) { e = __expf(xv - m3); s3 += e; }
            acc[cf][r] = e;
        }
#pragma unroll
        for (int o = 8; o; o >>= 1) {
            s0 += __shfl_xor(s0, o); s1 += __shfl_xor(s1, o);
            s2 += __shfl_xor(s2, o); s3 += __shfl_xor(s3, o);
        }
        float i0 = 1.f / s0, i1 = 1.f / s1, i2 = 1.f / s2, i3 = 1.f / s3;
        if (row < M) {
#pragma unroll
            for (int cf = 0; cf < 28; ++cf) {
                int colc = cf * 16 + l15;
                float e = acc[cf][r];
                if (colc < 350)                     o3[(size_t)row * 350 + colc]       = e * i0;
                else if (colc >= 352 && colc < 362) o0[(size_t)row * 10 + colc - 352]  = e * i1;
                else if (colc >= 362 && colc < 387) o1[(size_t)row * 25 + colc - 362]  = e * i2;
                else if (colc >= 387 && colc < 403) o2[(size_t)row * 16 + colc - 387]  = e * i3;
            }
        }
    }
}

// ---------------- launch ----------------
extern "C" void kernel_launch(void* const* d_in, const int* in_sizes, int n_in,
                              void* d_out, int out_size, void* d_ws, size_t ws_size,
                              hipStream_t stream)
{
    const float* x   = (const float*)d_in[0];
    const int*   ei  = (const int*)d_in[1];
    const float* W1  = (const float*)d_in[2];
    const float* b1  = (const float*)d_in[3];
    const float* Wg0 = (const float*)d_in[4];
    const float* bg0 = (const float*)d_in[5];
    const float* Wc0 = (const float*)d_in[6];
    const float* bc0 = (const float*)d_in[7];
    const float* Wg1 = (const float*)d_in[8];
    const float* bg1 = (const float*)d_in[9];
    const float* Wc1 = (const float*)d_in[10];
    const float* bc1 = (const float*)d_in[11];
    const float* Wg2 = (const float*)d_in[12];
    const float* bg2 = (const float*)d_in[13];
    const float* Wc2 = (const float*)d_in[14];
    const float* bc2 = (const float*)d_in[15];
    const float* Wg3 = (const float*)d_in[16];
    const float* bg3 = (const float*)d_in[17];
    const float* Wc3 = (const float*)d_in[18];
    const float* bc3 = (const float*)d_in[19];
    const int* srcI = ei;
    const int* dstI = ei + NE;

    char* ws = (char*)d_ws;
    size_t off = 0;
    auto alloc = [&](size_t bytes) { void* p = ws + off; off += (bytes + 255) & ~(size_t)255; return p; };
    float* dinv   = (float*)alloc(50176 * 4);
    int*   rowptr = (int*)  alloc(50432 * 4);
    int*   cnt    = (int*)  alloc(2 * 50176 * 4);   // cnt + cursor contiguous
    int*   cursor = cnt + 50176;
    int*   bsum   = (int*)  alloc(1024);
    int*   bsumx  = (int*)  alloc(1024);
    int*   col    = (int*)  alloc((size_t)NE * 4);
    unsigned short* W1t = (unsigned short*)alloc(256 * 512 * 2);
    unsigned short* Wft = (unsigned short*)alloc(448 * 256 * 2);
    float* bfv   = (float*)alloc(448 * 4);
    unsigned short* xwb = (unsigned short*)alloc((size_t)NN * HIDC * 2);
    unsigned short* hb  = (unsigned short*)alloc((size_t)NN * HIDC * 2);
    unsigned short* ahb = xwb;   // alias: xwb dead after gather1

    float* out0 = (float*)d_out;                     // type  [NN][10]
    float* out1 = out0 + (size_t)NN * 10;            // school[NN][25]
    float* out2 = out1 + (size_t)NN * 25;            // time  [NN][16]
    float* out3 = out2 + (size_t)NN * 16;            // author[NN][350]

    // ---- CSR build ----
    hipMemsetAsync(cnt, 0, 2 * 50176 * 4, stream);
    k_deg_count<<<(NE + 255) / 256, 256, 0, stream>>>(dstI, cnt, NE);
    k_scan1<<<NBLK, 256, 0, stream>>>(cnt, rowptr, bsum, dinv, NN);
    k_scan2<<<1, 256, 0, stream>>>(bsum, bsumx, NBLK);
    k_scan3<<<NBLK, 256, 0, stream>>>(rowptr, bsumx, NN, NE);
    k_fill<<<(NE + 255) / 256, 256, 0, stream>>>(srcI, dstI, rowptr, cursor, col, NE);

    // ---- weight prep (fused) ----
    k_prep<<<962, 256, 0, stream>>>(W1,
                                    Wg0, Wc0, bg0, bc0, Wg1, Wc1, bg1, bc1,
                                    Wg2, Wc2, bg2, bc2, Wg3, Wc3, bg3, bc3,
                                    W1t, Wft, bfv);

    // ---- pipeline ----
    gemm1_conv<<<(NN + 63) / 64, 256, 0, stream>>>(x, W1t, xwb, NN);
    k_gather2<true, true><<<(NN + 7) / 8, 256, 0, stream>>>(xwb, rowptr, col, dinv, b1, hb, NN);
    k_gather2<false, false><<<(NN + 7) / 8, 256, 0, stream>>>(hb, rowptr, col, dinv, nullptr, ahb, NN);
    gemm2_heads<<<(NN + 63) / 64, 256, 0, stream>>>(ahb, Wft, bfv, out0, out1, out2, out3, NN);
}